// Round 13
// baseline (201.640 us; speedup 1.0000x reference)
//
#include <hip/hip_runtime.h>
#include <hip/hip_fp16.h>

#define INPUT_SIZE 128
#define NUM_REL 16

typedef int      i32x4  __attribute__((ext_vector_type(4)));
typedef float    f32x4  __attribute__((ext_vector_type(4)));
typedef _Float16 f16x8  __attribute__((ext_vector_type(8)));

// ---------------------------------------------------------------------------
// R11's kernel 1 VERBATIM (MFMA): L[n][0:16)=x[n].w_src, L[n][16:32)=x[n].w_dst.
// ---------------------------------------------------------------------------
__global__ __launch_bounds__(256) void node_logits_mfma(
    const float* __restrict__ x,
    const float* __restrict__ w,     // (256,16) row-major
    __half* __restrict__ L,          // (num_nodes, 32) fp16
    int num_nodes)
{
    const int wave = threadIdx.x >> 6;
    const int lane = threadIdx.x & 63;
    const int m0 = (blockIdx.x * 4 + wave) * 16;
    if (m0 >= num_nodes) return;

    const int ln = lane & 15;        // A-row / B-col / D-col
    const int kg = lane >> 4;        // k-group 0..3

    f16x8 bfrag[2][4];
    #pragma unroll
    for (int t = 0; t < 2; ++t)
        #pragma unroll
        for (int ks = 0; ks < 4; ++ks)
            #pragma unroll
            for (int e = 0; e < 8; ++e) {
                const int k = ks * 32 + kg * 8 + e;
                const float v = (t == 0) ? w[k * NUM_REL + ln]
                                         : w[(INPUT_SIZE + k) * NUM_REL + ln];
                bfrag[t][ks][e] = (_Float16)v;
            }

    const int row = (m0 + ln < num_nodes) ? (m0 + ln) : (num_nodes - 1);
    const float* xr = x + (size_t)row * INPUT_SIZE;
    f16x8 afrag[4];
    #pragma unroll
    for (int ks = 0; ks < 4; ++ks) {
        const f32x4 lo = *(const f32x4*)(xr + ks * 32 + kg * 8);
        const f32x4 hi = *(const f32x4*)(xr + ks * 32 + kg * 8 + 4);
        #pragma unroll
        for (int e = 0; e < 4; ++e) {
            afrag[ks][e]     = (_Float16)lo[e];
            afrag[ks][4 + e] = (_Float16)hi[e];
        }
    }

    f32x4 acc0 = {0.f, 0.f, 0.f, 0.f};
    f32x4 acc1 = {0.f, 0.f, 0.f, 0.f};
    #pragma unroll
    for (int ks = 0; ks < 4; ++ks) {
        acc0 = __builtin_amdgcn_mfma_f32_16x16x32_f16(afrag[ks], bfrag[0][ks], acc0, 0, 0, 0);
        acc1 = __builtin_amdgcn_mfma_f32_16x16x32_f16(afrag[ks], bfrag[1][ks], acc1, 0, 0, 0);
    }

    #pragma unroll
    for (int q = 0; q < 4; ++q) {
        const int r = m0 + kg * 4 + q;
        if (r < num_nodes) {
            L[(size_t)r * 32 + ln]      = __float2half(acc0[q]);
            L[(size_t)r * 32 + 16 + ln] = __float2half(acc1[q]);
        }
    }
}

// ---------------------------------------------------------------------------
// R2/R11's kernel 2 VERBATIM. DIAGNOSTIC: launched NINE times (idempotent).
// T = k1m + 9*k2 + 8*g + f0  ->  k2+g = (T - 36.4)/8.
// Model B (f0~9): T ~ 235-250. Model A (f0~0): T ~ 165-185.
// ---------------------------------------------------------------------------
__global__ __launch_bounds__(256) void edge_score_kernel(
    const int* __restrict__ ei,      // (2, E) int32
    const int* __restrict__ et,      // (E,) int32
    const __half* __restrict__ L,    // (N, 32) fp16
    float* __restrict__ out,
    int num_edges)
{
    const int i = blockIdx.x * blockDim.x + threadIdx.x;   // octet index
    if (i * 8 >= num_edges) return;

    const i32x4* eis = (const i32x4*)ei;
    const i32x4* eid = (const i32x4*)(ei + num_edges);
    const i32x4* ett = (const i32x4*)et;

    const i32x4 sa = eis[2 * i], sb = eis[2 * i + 1];
    const i32x4 da = eid[2 * i], db = eid[2 * i + 1];
    const i32x4 ta = ett[2 * i], tb = ett[2 * i + 1];

    int s[8], d[8], t[8];
    #pragma unroll
    for (int j = 0; j < 4; ++j) {
        s[j] = sa[j]; s[4 + j] = sb[j];
        d[j] = da[j]; d[4 + j] = db[j];
        t[j] = ta[j]; t[4 + j] = tb[j];
    }

    __half hs[8], hd[8];
    #pragma unroll
    for (int j = 0; j < 8; ++j) hs[j] = L[(size_t)s[j] * 32 + t[j]];
    #pragma unroll
    for (int j = 0; j < 8; ++j) hd[j] = L[(size_t)d[j] * 32 + 16 + t[j]];

    f32x4 r[2];
    #pragma unroll
    for (int j = 0; j < 8; ++j) {
        const float sc = __half2float(hs[j]) + __half2float(hd[j]);
        const float att = 1.f / (1.f + __expf(-sc));
        r[j >> 2][j & 3] = fminf(fmaxf(att, 1e-5f), 0.99999f);
    }
    f32x4* o = (f32x4*)out;
    o[2 * i]     = r[0];
    o[2 * i + 1] = r[1];
}

// Fallback: direct per-edge dot product in f32 (no workspace).
__global__ void edge_direct_kernel(const float* __restrict__ x,
                                   const float* __restrict__ w,
                                   const int* __restrict__ ei,
                                   const int* __restrict__ et,
                                   float* __restrict__ out,
                                   int num_edges) {
    const int e = blockIdx.x * blockDim.x + threadIdx.x;
    if (e >= num_edges) return;
    const int s = ei[e];
    const int d = ei[num_edges + e];
    const int t = et[e];
    const float* xs = x + (size_t)s * INPUT_SIZE;
    const float* xd = x + (size_t)d * INPUT_SIZE;
    float acc = 0.f;
    #pragma unroll 4
    for (int k = 0; k < INPUT_SIZE; ++k)
        acc += xs[k] * w[k * NUM_REL + t] + xd[k] * w[(INPUT_SIZE + k) * NUM_REL + t];
    const float att = 1.f / (1.f + __expf(-acc));
    out[e] = fminf(fmaxf(att, 1e-5f), 0.99999f);
}

extern "C" void kernel_launch(void* const* d_in, const int* in_sizes, int n_in,
                              void* d_out, int out_size, void* d_ws, size_t ws_size,
                              hipStream_t stream) {
    const float* x  = (const float*)d_in[0];   // (50000, 128) f32
    const float* w  = (const float*)d_in[1];   // (256, 16) f32
    const int*   ei = (const int*)d_in[2];     // (2, E) int32
    const int*   et = (const int*)d_in[3];     // (E,) int32
    float* out = (float*)d_out;

    const int num_nodes = in_sizes[0] / INPUT_SIZE;
    const int num_edges = in_sizes[3];

    const size_t ws_needed = (size_t)num_nodes * 32 * sizeof(__half);

    if (ws_size >= ws_needed && (num_edges & 7) == 0) {
        __half* L = (__half*)d_ws;

        const int blocks1 = (num_nodes + 63) / 64;   // 64 nodes per block
        node_logits_mfma<<<blocks1, 256, 0, stream>>>(x, w, L, num_nodes);

        const int octs    = num_edges / 8;
        const int blocks2 = (octs + 255) / 256;
        // DIAGNOSTIC REPLICATION x9 (deterministic, idempotent).
        for (int rep = 0; rep < 9; ++rep)
            edge_score_kernel<<<blocks2, 256, 0, stream>>>(ei, et, L, out, num_edges);
    } else {
        const int blocks = (num_edges + 255) / 256;
        edge_direct_kernel<<<blocks, 256, 0, stream>>>(x, w, ei, et, out, num_edges);
    }
}

// Round 15
// 36.446 us; speedup vs baseline: 5.5326x; 5.5326x over previous
//
#include <hip/hip_runtime.h>
#include <hip/hip_fp16.h>

#define INPUT_SIZE 128
#define NUM_REL 16

typedef int      i32x4  __attribute__((ext_vector_type(4)));
typedef float    f32x4  __attribute__((ext_vector_type(4)));
typedef __fp16   h16x2  __attribute__((ext_vector_type(2)));   // cvt_pkrtz return type
typedef _Float16 f16x8  __attribute__((ext_vector_type(8)));

// ---------------------------------------------------------------------------
// Kernel 1 (MFMA, v2): L[n][0:16)=x[n].w_src, L[n][16:32)=x[n].w_dst.
// R14 changes vs R11 (measured k1m ~8.3 us vs ~6 floor):
//   1. A-loads (HBM, ~900cy) issued FIRST; B-loads (L2) + converts fill the
//      latency shadow (only 3 waves/SIMD -> ILP must cover latency).
//   2. Packed cvt_pkrtz for A/B input conversion (halves VALU cvt count).
//      RTZ on inputs only; final stores remain RNE.
// Layouts (verified passing since R11): A row=l&15 k=(l>>4)*8+e; B col=l&15
// same k; D col=l&15 row=(l>>4)*4+q.
// ---------------------------------------------------------------------------
__global__ __launch_bounds__(256) void node_logits_mfma(
    const float* __restrict__ x,
    const float* __restrict__ w,     // (256,16) row-major
    __half* __restrict__ L,          // (num_nodes, 32) fp16
    int num_nodes)
{
    const int wave = threadIdx.x >> 6;
    const int lane = threadIdx.x & 63;
    const int m0 = (blockIdx.x * 4 + wave) * 16;
    if (m0 >= num_nodes) return;

    const int ln = lane & 15;        // A-row / B-col / D-col
    const int kg = lane >> 4;        // k-group 0..3

    // --- A loads first: 8 independent 16B HBM loads in flight. ---
    const int row = (m0 + ln < num_nodes) ? (m0 + ln) : (num_nodes - 1);
    const float* xr = x + (size_t)row * INPUT_SIZE;
    f32x4 alo[4], ahi[4];
    #pragma unroll
    for (int ks = 0; ks < 4; ++ks) {
        alo[ks] = *(const f32x4*)(xr + ks * 32 + kg * 8);
        ahi[ks] = *(const f32x4*)(xr + ks * 32 + kg * 8 + 4);
    }

    // --- B loads (L2-hot) + packed converts, in the A-latency shadow. ---
    f16x8 bfrag[2][4];
    #pragma unroll
    for (int t = 0; t < 2; ++t)
        #pragma unroll
        for (int ks = 0; ks < 4; ++ks) {
            union { f16x8 v; h16x2 p[4]; } u;
            #pragma unroll
            for (int ep = 0; ep < 4; ++ep) {
                const int k = ks * 32 + kg * 8 + ep * 2;
                const float v0 = w[(size_t)(t * INPUT_SIZE + k)     * NUM_REL + ln];
                const float v1 = w[(size_t)(t * INPUT_SIZE + k + 1) * NUM_REL + ln];
                u.p[ep] = __builtin_amdgcn_cvt_pkrtz(v0, v1);
            }
            bfrag[t][ks] = u.v;
        }

    // --- A converts (packed). ---
    f16x8 afrag[4];
    #pragma unroll
    for (int ks = 0; ks < 4; ++ks) {
        union { f16x8 v; h16x2 p[4]; } u;
        u.p[0] = __builtin_amdgcn_cvt_pkrtz(alo[ks][0], alo[ks][1]);
        u.p[1] = __builtin_amdgcn_cvt_pkrtz(alo[ks][2], alo[ks][3]);
        u.p[2] = __builtin_amdgcn_cvt_pkrtz(ahi[ks][0], ahi[ks][1]);
        u.p[3] = __builtin_amdgcn_cvt_pkrtz(ahi[ks][2], ahi[ks][3]);
        afrag[ks] = u.v;
    }

    f32x4 acc0 = {0.f, 0.f, 0.f, 0.f};
    f32x4 acc1 = {0.f, 0.f, 0.f, 0.f};
    #pragma unroll
    for (int ks = 0; ks < 4; ++ks) {
        acc0 = __builtin_amdgcn_mfma_f32_16x16x32_f16(afrag[ks], bfrag[0][ks], acc0, 0, 0, 0);
        acc1 = __builtin_amdgcn_mfma_f32_16x16x32_f16(afrag[ks], bfrag[1][ks], acc1, 0, 0, 0);
    }

    // Store (RNE): node r = m0 + kg*4 + q; rel = ln (acc0) / 16+ln (acc1).
    #pragma unroll
    for (int q = 0; q < 4; ++q) {
        const int r = m0 + kg * 4 + q;
        if (r < num_nodes) {
            L[(size_t)r * 32 + ln]      = __float2half(acc0[q]);
            L[(size_t)r * 32 + 16 + ln] = __float2half(acc1[q]);
        }
    }
}

// ---------------------------------------------------------------------------
// Kernel 2 VERBATIM (R2/R11 shape; measured ~19 us, request-throughput-bound:
// 3.2M scattered line-requests ~ 10.4 us L2-service floor + streams + fills.
// Six structural levers nulled R3-R9 — do not touch).
// ---------------------------------------------------------------------------
__global__ __launch_bounds__(256) void edge_score_kernel(
    const int* __restrict__ ei,      // (2, E) int32
    const int* __restrict__ et,      // (E,) int32
    const __half* __restrict__ L,    // (N, 32) fp16
    float* __restrict__ out,
    int num_edges)
{
    const int i = blockIdx.x * blockDim.x + threadIdx.x;   // octet index
    if (i * 8 >= num_edges) return;

    const i32x4* eis = (const i32x4*)ei;
    const i32x4* eid = (const i32x4*)(ei + num_edges);
    const i32x4* ett = (const i32x4*)et;

    const i32x4 sa = eis[2 * i], sb = eis[2 * i + 1];
    const i32x4 da = eid[2 * i], db = eid[2 * i + 1];
    const i32x4 ta = ett[2 * i], tb = ett[2 * i + 1];

    int s[8], d[8], t[8];
    #pragma unroll
    for (int j = 0; j < 4; ++j) {
        s[j] = sa[j]; s[4 + j] = sb[j];
        d[j] = da[j]; d[4 + j] = db[j];
        t[j] = ta[j]; t[4 + j] = tb[j];
    }

    __half hs[8], hd[8];
    #pragma unroll
    for (int j = 0; j < 8; ++j) hs[j] = L[(size_t)s[j] * 32 + t[j]];
    #pragma unroll
    for (int j = 0; j < 8; ++j) hd[j] = L[(size_t)d[j] * 32 + 16 + t[j]];

    f32x4 r[2];
    #pragma unroll
    for (int j = 0; j < 8; ++j) {
        const float sc = __half2float(hs[j]) + __half2float(hd[j]);
        const float att = 1.f / (1.f + __expf(-sc));
        r[j >> 2][j & 3] = fminf(fmaxf(att, 1e-5f), 0.99999f);
    }
    f32x4* o = (f32x4*)out;
    o[2 * i]     = r[0];
    o[2 * i + 1] = r[1];
}

// Fallback: direct per-edge dot product in f32 (no workspace).
__global__ void edge_direct_kernel(const float* __restrict__ x,
                                   const float* __restrict__ w,
                                   const int* __restrict__ ei,
                                   const int* __restrict__ et,
                                   float* __restrict__ out,
                                   int num_edges) {
    const int e = blockIdx.x * blockDim.x + threadIdx.x;
    if (e >= num_edges) return;
    const int s = ei[e];
    const int d = ei[num_edges + e];
    const int t = et[e];
    const float* xs = x + (size_t)s * INPUT_SIZE;
    const float* xd = x + (size_t)d * INPUT_SIZE;
    float acc = 0.f;
    #pragma unroll 4
    for (int k = 0; k < INPUT_SIZE; ++k)
        acc += xs[k] * w[k * NUM_REL + t] + xd[k] * w[(INPUT_SIZE + k) * NUM_REL + t];
    const float att = 1.f / (1.f + __expf(-acc));
    out[e] = fminf(fmaxf(att, 1e-5f), 0.99999f);
}

extern "C" void kernel_launch(void* const* d_in, const int* in_sizes, int n_in,
                              void* d_out, int out_size, void* d_ws, size_t ws_size,
                              hipStream_t stream) {
    const float* x  = (const float*)d_in[0];   // (50000, 128) f32
    const float* w  = (const float*)d_in[1];   // (256, 16) f32
    const int*   ei = (const int*)d_in[2];     // (2, E) int32
    const int*   et = (const int*)d_in[3];     // (E,) int32
    float* out = (float*)d_out;

    const int num_nodes = in_sizes[0] / INPUT_SIZE;
    const int num_edges = in_sizes[3];

    const size_t ws_needed = (size_t)num_nodes * 32 * sizeof(__half);

    if (ws_size >= ws_needed && (num_edges & 7) == 0) {
        __half* L = (__half*)d_ws;

        const int blocks1 = (num_nodes + 63) / 64;   // 64 nodes per block
        node_logits_mfma<<<blocks1, 256, 0, stream>>>(x, w, L, num_nodes);

        const int octs    = num_edges / 8;
        const int blocks2 = (octs + 255) / 256;
        edge_score_kernel<<<blocks2, 256, 0, stream>>>(ei, et, L, out, num_edges);
    } else {
        const int blocks = (num_edges + 255) / 256;
        edge_direct_kernel<<<blocks, 256, 0, stream>>>(x, w, ei, et, out, num_edges);
    }
}